// Round 10
// baseline (1125.553 us; speedup 1.0000x reference)
//
#include <hip/hip_runtime.h>
#include <hip/hip_fp16.h>

#define FDIM 64
#define BUCK_SHIFT 8          // 256 nodes per bucket
#define BUCK_R 256
#define BCAP 8192             // slots per bucket (mean ~3070, 18 sigma headroom)
#define GSTRIDE 8             // ints between gcount counters (32B atomic granule)
#define PB_EDGES 8192         // edges per bucket_place block
#define MAXBUCK 512

// ---- detect whether edge_index is int64 (high dwords all zero) or int32 ----
__global__ void detect_dtype_kernel(const int* ei, int nsamp, int* flag) {
    __shared__ int any_nz;
    if (threadIdx.x == 0) any_nz = 0;
    __syncthreads();
    int local = 0;
    for (int i = threadIdx.x; i < nsamp; i += blockDim.x) {
        if (ei[2 * i + 1] != 0) local = 1;   // odd dword: int64 high word (==0) vs real int32 index
    }
    if (local) atomicOr(&any_nz, 1);
    __syncthreads();
    if (threadIdx.x == 0) flag[0] = (any_nz == 0) ? 1 : 0;   // 1 => int64
}

// ---- single pass: bucket edges by dst>>8 into fixed-capacity slabs.
// Per-block LDS histogram; ONE global atomic per (block,bucket); no scan. ----
__global__ __launch_bounds__(256) void bucket_place(const void* ei, const int* flag, int E,
                                                    int nbuck,
                                                    int* __restrict__ gcount,
                                                    int2* __restrict__ parts) {
    __shared__ int lhist[MAXBUCK];
    __shared__ int loff[MAXBUCK];
    __shared__ int lbase[MAXBUCK];
    int is64 = flag[0];
    int t = threadIdx.x;
    const long long* q64 = (const long long*)ei;
    const int* q32 = (const int*)ei;
    int base = blockIdx.x * PB_EDGES;
    for (int i = t; i < nbuck; i += 256) { lhist[i] = 0; loff[i] = 0; }
    __syncthreads();
    // phase A: local histogram (dst only)
    #pragma unroll 4
    for (int u = 0; u < PB_EDGES / 256; u++) {
        int i = base + u * 256 + t;
        if (i < E) {
            int d = is64 ? (int)q64[E + i] : q32[E + i];
            atomicAdd(&lhist[d >> BUCK_SHIFT], 1);
        }
    }
    __syncthreads();
    // reserve: one global atomic per touched bucket
    for (int i = t; i < nbuck; i += 256)
        lbase[i] = (lhist[i] > 0) ? atomicAdd(&gcount[i * GSTRIDE], lhist[i]) : 0;
    __syncthreads();
    // phase B: re-read (L2/L3-hot), rank via LDS rtn-atomic, write runs
    #pragma unroll 4
    for (int u = 0; u < PB_EDGES / 256; u++) {
        int i = base + u * 256 + t;
        if (i < E) {
            int s, d;
            if (is64) { s = (int)q64[i]; d = (int)q64[E + i]; }
            else      { s = q32[i];      d = q32[E + i]; }
            int bk = d >> BUCK_SHIFT;
            int off = atomicAdd(&loff[bk], 1);
            int pos = lbase[bk] + off;
            if (pos < BCAP) parts[(size_t)bk * BCAP + pos] = make_int2(s, d);
        }
    }
}

// ---- per-bucket degree count -> dinv = rsqrt(deg+1) ----
__global__ __launch_bounds__(256) void dinv_from_buckets(const int2* __restrict__ parts,
                                                         const int* __restrict__ gcount,
                                                         float* __restrict__ dinv, int N) {
    __shared__ int cnt[BUCK_R];
    int bkt = blockIdx.x;
    int t = threadIdx.x;
    cnt[t] = 0;
    __syncthreads();
    int c = gcount[bkt * GSTRIDE]; if (c > BCAP) c = BCAP;
    const int2* pg = parts + (size_t)bkt * BCAP;
    for (int j = t; j < c; j += 256) atomicAdd(&cnt[pg[j].y & (BUCK_R - 1)], 1);
    __syncthreads();
    int n = (bkt << BUCK_SHIFT) + t;
    if (n < N) dinv[n] = rsqrtf((float)(cnt[t] + 1));
}

// ---- y16[n,:] = half((x[n,:] @ W) * dinv[n]) — LDS-tiled 64x64 ----
template <typename TIN>
__global__ __launch_bounds__(256, 4) void gemm_scale(const TIN* __restrict__ x,
                                                     const float* __restrict__ W,
                                                     const float* __restrict__ dinv,
                                                     __half* __restrict__ y16, int N) {
    __shared__ float Xl[64 * 68];   // pad to 68 to break bank aliasing
    __shared__ float Wl[64 * 64];
    int t = threadIdx.x;
    int nbase = blockIdx.x * 64;
    for (int i = t; i < 1024; i += 256) {
        ((float4*)Wl)[i] = ((const float4*)W)[i];
    }
    for (int i = t; i < 1024; i += 256) {
        int flat = i * 4;
        int n = flat >> 6, k = flat & 63;
        int g = nbase + n;
        float4 v;
        if (g < N) {
            if constexpr (sizeof(TIN) == 2) {
                const __half2* hp = (const __half2*)((const __half*)x + (size_t)g * FDIM + k);
                float2 a = __half22float2(hp[0]);
                float2 c = __half22float2(hp[1]);
                v = make_float4(a.x, a.y, c.x, c.y);
            } else {
                v = *(const float4*)((const float*)x + (size_t)g * FDIM + k);
            }
        } else {
            v = make_float4(0.f, 0.f, 0.f, 0.f);
        }
        *(float4*)&Xl[n * 68 + k] = v;
    }
    __syncthreads();

    int fr = t & 15;    // feature group: feats fr*4..fr*4+3
    int ng = t >> 4;    // node group:    nodes ng*4..ng*4+3
    float acc[4][4] = {{0.f}};
    #pragma unroll 4
    for (int kc = 0; kc < 16; kc++) {
        float4 xa[4], wa[4];
        #pragma unroll
        for (int i = 0; i < 4; i++) xa[i] = *(float4*)&Xl[(ng * 4 + i) * 68 + kc * 4];
        #pragma unroll
        for (int j = 0; j < 4; j++) wa[j] = *(float4*)&Wl[(kc * 4 + j) * 64 + fr * 4];
        #pragma unroll
        for (int i = 0; i < 4; i++) {
            acc[i][0] += xa[i].x * wa[0].x + xa[i].y * wa[1].x + xa[i].z * wa[2].x + xa[i].w * wa[3].x;
            acc[i][1] += xa[i].x * wa[0].y + xa[i].y * wa[1].y + xa[i].z * wa[2].y + xa[i].w * wa[3].y;
            acc[i][2] += xa[i].x * wa[0].z + xa[i].y * wa[1].z + xa[i].z * wa[2].z + xa[i].w * wa[3].z;
            acc[i][3] += xa[i].x * wa[0].w + xa[i].y * wa[1].w + xa[i].z * wa[2].w + xa[i].w * wa[3].w;
        }
    }
    #pragma unroll
    for (int i = 0; i < 4; i++) {
        int g = nbase + ng * 4 + i;
        if (g < N) {
            float dv = dinv[g];
            __half2 ha = __floats2half2_rn(acc[i][0] * dv, acc[i][1] * dv);
            __half2 hb = __floats2half2_rn(acc[i][2] * dv, acc[i][3] * dv);
            union { __half2 h[2]; uint2 u; } cvt;
            cvt.h[0] = ha; cvt.h[1] = hb;
            *(uint2*)(y16 + (size_t)g * FDIM + fr * 4) = cvt.u;
        }
    }
}

__device__ __forceinline__ float4 half4_to_float4(uint2 u) {
    float2 a = __half22float2(*(__half2*)&u.x);
    float2 b = __half22float2(*(__half2*)&u.y);
    return make_float4(a.x, a.y, b.x, b.y);
}

// ---- gather via LDS accumulation: block <- bucket of 256 dst nodes.
// acc[r][c] at LDS index r*64 + (c ^ (r&31))  (XOR spreads banks across rows).
// Wave step: 4 edges x 16 lanes (one 128B y16 row each), ds_add_f32 accumulate.
// Epilogue: out[n,:] = dinv[n]*(acc[n,:] + y16[n,:]) + b (+ReLU), coalesced. ----
template <bool RELU, typename OUT_T>
__global__ __launch_bounds__(256) void gather_lds(const int2* __restrict__ parts,
                                                  const int* __restrict__ gcount,
                                                  const __half* __restrict__ y16,
                                                  const float* __restrict__ dinv,
                                                  const float* __restrict__ b,
                                                  OUT_T* __restrict__ out, int N) {
    __shared__ float acc[BUCK_R * FDIM];   // 64 KB
    int bkt = blockIdx.x;
    int t = threadIdx.x;
    int lane = t & 63;
    int wid = t >> 6;        // wave 0..3
    int nbase = bkt << BUCK_SHIFT;
    #pragma unroll
    for (int i = 0; i < BUCK_R * FDIM / 4; i += 256)
        ((float4*)acc)[i + t] = make_float4(0.f, 0.f, 0.f, 0.f);
    __syncthreads();

    int cnt = gcount[bkt * GSTRIDE]; if (cnt > BCAP) cnt = BCAP;
    const int2* pg = parts + (size_t)bkt * BCAP;
    int f = lane & 15;       // feature quad (halves 4f..4f+3)
    int eo = lane >> 4;      // edge slot 0..3 within wave step

    for (int j0 = wid * 8; j0 < cnt; j0 += 32) {   // 8 edges per wave per iter
        int e0 = j0 + eo;
        int e1 = j0 + 4 + eo;
        bool v0 = e0 < cnt, v1 = e1 < cnt;
        int2 sd0 = v0 ? pg[e0] : make_int2(0, 0);
        int2 sd1 = v1 ? pg[e1] : make_int2(0, 0);
        uint2 u0 = *(const uint2*)(y16 + (size_t)sd0.x * FDIM + 4 * f);
        uint2 u1 = *(const uint2*)(y16 + (size_t)sd1.x * FDIM + 4 * f);
        if (v0) {
            float4 fv = half4_to_float4(u0);
            int r = sd0.y & (BUCK_R - 1);
            int cb = 4 * f, x = r & 31, rb = r * FDIM;
            atomicAdd(&acc[rb + ((cb + 0) ^ x)], fv.x);
            atomicAdd(&acc[rb + ((cb + 1) ^ x)], fv.y);
            atomicAdd(&acc[rb + ((cb + 2) ^ x)], fv.z);
            atomicAdd(&acc[rb + ((cb + 3) ^ x)], fv.w);
        }
        if (v1) {
            float4 fv = half4_to_float4(u1);
            int r = sd1.y & (BUCK_R - 1);
            int cb = 4 * f, x = r & 31, rb = r * FDIM;
            atomicAdd(&acc[rb + ((cb + 0) ^ x)], fv.x);
            atomicAdd(&acc[rb + ((cb + 1) ^ x)], fv.y);
            atomicAdd(&acc[rb + ((cb + 2) ^ x)], fv.z);
            atomicAdd(&acc[rb + ((cb + 3) ^ x)], fv.w);
        }
    }
    __syncthreads();

    // epilogue: 4 passes x 64 rows; 4 threads per row, 16 feats per thread
    #pragma unroll
    for (int rr = 0; rr < 4; rr++) {
        int r = rr * 64 + (t >> 2);
        int n = nbase + r;
        if (n < N) {
            int c0 = (t & 3) * 16;
            int x = r & 31, rb = r * FDIM;
            float dv = dinv[n];
            const uint2* ys = (const uint2*)(y16 + (size_t)n * FDIM + c0);
            float o[16];
            #pragma unroll
            for (int q = 0; q < 4; q++) {
                float4 sf = half4_to_float4(ys[q]);
                float4 bb = ((const float4*)b)[(c0 >> 2) + q];
                float sv[4] = {sf.x, sf.y, sf.z, sf.w};
                float bv[4] = {bb.x, bb.y, bb.z, bb.w};
                #pragma unroll
                for (int k = 0; k < 4; k++) {
                    int c = c0 + q * 4 + k;
                    float v = acc[rb + (c ^ x)] + sv[k];
                    v = v * dv + bv[k];
                    if (RELU) v = fmaxf(v, 0.f);
                    o[q * 4 + k] = v;
                }
            }
            if constexpr (sizeof(OUT_T) == 2) {
                union { __half2 h[2]; uint2 u; } cv;
                uint2* op = (uint2*)((__half*)out + (size_t)n * FDIM + c0);
                #pragma unroll
                for (int q = 0; q < 4; q++) {
                    cv.h[0] = __floats2half2_rn(o[q * 4 + 0], o[q * 4 + 1]);
                    cv.h[1] = __floats2half2_rn(o[q * 4 + 2], o[q * 4 + 3]);
                    op[q] = cv.u;
                }
            } else {
                float4* op = (float4*)((float*)out + (size_t)n * FDIM + c0);
                #pragma unroll
                for (int q = 0; q < 4; q++)
                    op[q] = make_float4(o[q * 4 + 0], o[q * 4 + 1], o[q * 4 + 2], o[q * 4 + 3]);
            }
        }
    }
}

static inline size_t roundup256(size_t x) { return (x + 255) & ~(size_t)255; }

extern "C" void kernel_launch(void* const* d_in, const int* in_sizes, int n_in,
                              void* d_out, int out_size, void* d_ws, size_t ws_size,
                              hipStream_t stream) {
    const float* x  = (const float*)d_in[0];
    const void*  ei = d_in[1];
    const float* W1 = (const float*)d_in[2];
    const float* b1 = (const float*)d_in[3];
    const float* W2 = (const float*)d_in[4];
    const float* b2 = (const float*)d_in[5];
    float* out = (float*)d_out;

    int N = out_size / FDIM;                       // 100000
    int E = in_sizes[1] / 2;                       // 1200000
    int nbuck = (N + BUCK_R - 1) >> BUCK_SHIFT;    // 391
    if (nbuck > MAXBUCK) nbuck = MAXBUCK;          // (N<=131072 assumed)
    int nblk_p = (E + PB_EDGES - 1) / PB_EDGES;    // 147

    // ws layout (256B-aligned slots)
    char* p = (char*)d_ws;
    float* dinv  = (float*)p;  p += roundup256((size_t)N * 4);
    __half* y16  = (__half*)p; p += roundup256((size_t)N * FDIM * 2);
    __half* h16  = (__half*)p; p += roundup256((size_t)N * FDIM * 2);
    int* gcount  = (int*)p;    p += (size_t)MAXBUCK * GSTRIDE * 4;   // 16 KB
    int* flag    = (int*)p;    p += 256;
    int2* parts  = (int2*)p;   p += (size_t)nbuck * BCAP * sizeof(int2);  // ~25.6 MB

    hipMemsetAsync(gcount, 0, (size_t)MAXBUCK * GSTRIDE * 4, stream);

    // ---- graph prep: bucketize + degree ----
    detect_dtype_kernel<<<1, 256, 0, stream>>>((const int*)ei, 2048, flag);
    bucket_place<<<nblk_p, 256, 0, stream>>>(ei, flag, E, nbuck, gcount, parts);
    dinv_from_buckets<<<nbuck, 256, 0, stream>>>(parts, gcount, dinv, N);

    int gemm_grid = (N + 63) / 64;

    // ---- layer 1: h = relu(GCNConv(x, W1, b1)) -> h16 (fp16) ----
    gemm_scale<float><<<gemm_grid, 256, 0, stream>>>(x, W1, dinv, y16, N);
    gather_lds<true, __half><<<nbuck, 256, 0, stream>>>(parts, gcount, y16, dinv, b1, h16, N);

    // ---- layer 2: out = GCNConv(h, W2, b2) -> fp32 d_out ----
    gemm_scale<__half><<<gemm_grid, 256, 0, stream>>>(h16, W2, dinv, y16, N);
    gather_lds<false, float><<<nbuck, 256, 0, stream>>>(parts, gcount, y16, dinv, b2, out, N);
}

// Round 11
// 189.812 us; speedup vs baseline: 5.9298x; 5.9298x over previous
//
#include <hip/hip_runtime.h>
#include <hip/hip_fp16.h>

#define FDIM 64
#define SEG 512               // nodes per segment
#define SEG_SHIFT 9
#define NSEGMAX 256
#define SCAP 8192             // slots per segment slab (mean ~6.1K, ~26 sigma headroom)
#define GSTRIDE 8             // ints between per-segment counters
#define PB_EDGES 8192         // edges per bucket_place block

// ---- detect whether edge_index is int64 (high dwords all zero) or int32 ----
__global__ void detect_dtype_kernel(const int* ei, int nsamp, int* flag) {
    __shared__ int any_nz;
    if (threadIdx.x == 0) any_nz = 0;
    __syncthreads();
    int local = 0;
    for (int i = threadIdx.x; i < nsamp; i += blockDim.x) {
        if (ei[2 * i + 1] != 0) local = 1;   // odd dword: int64 high word (==0) vs real int32 index
    }
    if (local) atomicOr(&any_nz, 1);
    __syncthreads();
    if (threadIdx.x == 0) flag[0] = (any_nz == 0) ? 1 : 0;   // 1 => int64
}

// ---- pass 1 over edges: slab (s,d) by segment d>>9. LDS histogram; one global
// atomic per (block,segment); NO per-edge global atomics. ----
__global__ __launch_bounds__(256) void bucket_place(const void* ei, const int* flag, int E,
                                                    int nseg,
                                                    int* __restrict__ gcount,
                                                    int2* __restrict__ parts) {
    __shared__ int lhist[NSEGMAX];
    __shared__ int lbase[NSEGMAX];
    __shared__ int loff[NSEGMAX];
    int is64 = flag[0];
    int t = threadIdx.x;
    const long long* q64 = (const long long*)ei;
    const int* q32 = (const int*)ei;
    int base = blockIdx.x * PB_EDGES;
    for (int i = t; i < nseg; i += 256) { lhist[i] = 0; loff[i] = 0; }
    __syncthreads();
    // phase A: local histogram (dst only)
    #pragma unroll 4
    for (int u = 0; u < PB_EDGES / 256; u++) {
        int i = base + u * 256 + t;
        if (i < E) {
            int d = is64 ? (int)q64[E + i] : q32[E + i];
            atomicAdd(&lhist[d >> SEG_SHIFT], 1);
        }
    }
    __syncthreads();
    // reserve: one global atomic per touched segment
    for (int i = t; i < nseg; i += 256)
        lbase[i] = (lhist[i] > 0) ? atomicAdd(&gcount[i * GSTRIDE], lhist[i]) : 0;
    __syncthreads();
    // phase B: re-read (cache-hot), rank via LDS rtn-atomic, write runs
    #pragma unroll 4
    for (int u = 0; u < PB_EDGES / 256; u++) {
        int i = base + u * 256 + t;
        if (i < E) {
            int s, d;
            if (is64) { s = (int)q64[i]; d = (int)q64[E + i]; }
            else      { s = q32[i];      d = q32[E + i]; }
            int bk = d >> SEG_SHIFT;
            int off = atomicAdd(&loff[bk], 1);
            int pos = lbase[bk] + off;
            if (pos < SCAP) parts[(size_t)bk * SCAP + pos] = make_int2(s, d);
        }
    }
}

// ---- pass 2: per-segment counting sort. One block per 512-node segment:
// LDS hist -> LDS scan -> rowstart/deg/dinv (coalesced) -> place src into csr
// via LDS cursor atomics. csr scatter stays inside a 32KB L2-resident window. ----
__global__ __launch_bounds__(256) void place_sort(const int2* __restrict__ parts,
                                                  const int* __restrict__ gcount,
                                                  int* __restrict__ csr,
                                                  int* __restrict__ rowstart,
                                                  int* __restrict__ degv,
                                                  float* __restrict__ dinv, int N) {
    __shared__ int hist[SEG];
    __shared__ int cur[SEG];
    __shared__ int A[256], B[256];
    int s = blockIdx.x;
    int t = threadIdx.x;
    int nbase = s << SEG_SHIFT;
    hist[t] = 0; hist[t + 256] = 0;
    __syncthreads();
    int cnt = gcount[s * GSTRIDE]; if (cnt > SCAP) cnt = SCAP;
    const int2* pg = parts + (size_t)s * SCAP;
    for (int j = t; j < cnt; j += 256) atomicAdd(&hist[pg[j].y & (SEG - 1)], 1);
    __syncthreads();
    // exclusive scan over 512 via pair-sum + 256-wide Hillis-Steele
    int p = hist[2 * t] + hist[2 * t + 1];
    A[t] = p; __syncthreads();
    int* in = A; int* out = B;
    for (int off = 1; off < 256; off <<= 1) {
        out[t] = in[t] + ((t >= off) ? in[t - off] : 0);
        __syncthreads();
        int* z = in; in = out; out = z;
    }
    int esc = (t == 0) ? 0 : in[t - 1];
    cur[2 * t] = esc;
    cur[2 * t + 1] = esc + hist[2 * t];
    __syncthreads();
    // emit per-node metadata (coalesced)
    for (int i = t; i < SEG; i += 256) {
        int n = nbase + i;
        if (n < N) {
            rowstart[n] = s * SCAP + cur[i];
            degv[n] = hist[i];
            dinv[n] = rsqrtf((float)(hist[i] + 1));
        }
    }
    __syncthreads();
    // place: LDS cursor atomics only
    for (int j = t; j < cnt; j += 256) {
        int2 e = pg[j];
        int r = e.y & (SEG - 1);
        int off = atomicAdd(&cur[r], 1);
        csr[(size_t)s * SCAP + off] = e.x;
    }
}

// ---- y16[n,:] = half((x[n,:] @ W) * dinv[n]) — LDS-tiled 64x64 ----
template <typename TIN>
__global__ __launch_bounds__(256, 4) void gemm_scale(const TIN* __restrict__ x,
                                                     const float* __restrict__ W,
                                                     const float* __restrict__ dinv,
                                                     __half* __restrict__ y16, int N) {
    __shared__ float Xl[64 * 68];   // pad to 68 to break bank aliasing
    __shared__ float Wl[64 * 64];
    int t = threadIdx.x;
    int nbase = blockIdx.x * 64;
    for (int i = t; i < 1024; i += 256) {
        ((float4*)Wl)[i] = ((const float4*)W)[i];
    }
    for (int i = t; i < 1024; i += 256) {
        int flat = i * 4;
        int n = flat >> 6, k = flat & 63;
        int g = nbase + n;
        float4 v;
        if (g < N) {
            if constexpr (sizeof(TIN) == 2) {
                const __half2* hp = (const __half2*)((const __half*)x + (size_t)g * FDIM + k);
                float2 a = __half22float2(hp[0]);
                float2 c = __half22float2(hp[1]);
                v = make_float4(a.x, a.y, c.x, c.y);
            } else {
                v = *(const float4*)((const float*)x + (size_t)g * FDIM + k);
            }
        } else {
            v = make_float4(0.f, 0.f, 0.f, 0.f);
        }
        *(float4*)&Xl[n * 68 + k] = v;
    }
    __syncthreads();

    int fr = t & 15;    // feature group: feats fr*4..fr*4+3
    int ng = t >> 4;    // node group:    nodes ng*4..ng*4+3
    float acc[4][4] = {{0.f}};
    #pragma unroll 4
    for (int kc = 0; kc < 16; kc++) {
        float4 xa[4], wa[4];
        #pragma unroll
        for (int i = 0; i < 4; i++) xa[i] = *(float4*)&Xl[(ng * 4 + i) * 68 + kc * 4];
        #pragma unroll
        for (int j = 0; j < 4; j++) wa[j] = *(float4*)&Wl[(kc * 4 + j) * 64 + fr * 4];
        #pragma unroll
        for (int i = 0; i < 4; i++) {
            acc[i][0] += xa[i].x * wa[0].x + xa[i].y * wa[1].x + xa[i].z * wa[2].x + xa[i].w * wa[3].x;
            acc[i][1] += xa[i].x * wa[0].y + xa[i].y * wa[1].y + xa[i].z * wa[2].y + xa[i].w * wa[3].y;
            acc[i][2] += xa[i].x * wa[0].z + xa[i].y * wa[1].z + xa[i].z * wa[2].z + xa[i].w * wa[3].z;
            acc[i][3] += xa[i].x * wa[0].w + xa[i].y * wa[1].w + xa[i].z * wa[2].w + xa[i].w * wa[3].w;
        }
    }
    #pragma unroll
    for (int i = 0; i < 4; i++) {
        int g = nbase + ng * 4 + i;
        if (g < N) {
            float dv = dinv[g];
            __half2 ha = __floats2half2_rn(acc[i][0] * dv, acc[i][1] * dv);
            __half2 hb = __floats2half2_rn(acc[i][2] * dv, acc[i][3] * dv);
            union { __half2 h[2]; uint2 u; } cvt;
            cvt.h[0] = ha; cvt.h[1] = hb;
            *(uint2*)(y16 + (size_t)g * FDIM + fr * 4) = cvt.u;
        }
    }
}

__device__ __forceinline__ float4 half4_to_float4(uint2 u) {
    float2 a = __half22float2(*(__half2*)&u.x);
    float2 b = __half22float2(*(__half2*)&u.y);
    return make_float4(a.x, a.y, b.x, b.y);
}

// ---- gather: out[n,:] = dinv[n]*(y[n,:] + sum_bucket y[src,:]) + b (+ReLU) ----
// 4 edge streams x 16-lane rows: lane = 16*q + fl; each lane holds feats 4fl..4fl+3
// (uint2 = 4 halves). Streams combined via shfl_xor(16), shfl_xor(32).
template <bool RELU, typename OUT_T>
__global__ __launch_bounds__(256) void gather(const int* __restrict__ rowstart,
                                              const int* __restrict__ degv,
                                              const int* __restrict__ csr,
                                              const __half* __restrict__ y16,
                                              const float* __restrict__ dinv,
                                              const float* __restrict__ b,
                                              OUT_T* __restrict__ out, int N) {
    int lane = threadIdx.x & 63;
    int n = blockIdx.x * 4 + (threadIdx.x >> 6);
    if (n >= N) return;
    int q = lane >> 4;       // edge stream 0..3
    int fl = lane & 15;      // feature quad: feats 4fl..4fl+3
    int start = rowstart[n];
    int end = start + degv[n];
    float ax = 0.f, ay = 0.f, az = 0.f, aw = 0.f;
    for (int base = start; base < end; base += 64) {
        int m = end - base; if (m > 64) m = 64;
        int idx = (lane < m) ? csr[base + lane] : 0;
        int j = 0;
        for (; j + 7 < m; j += 8) {            // 8 edges via 2 row-loads/lane
            int s0 = __shfl(idx, j + q);
            int s1 = __shfl(idx, j + 4 + q);
            uint2 u0 = *(const uint2*)(y16 + (size_t)s0 * FDIM + 4 * fl);
            uint2 u1 = *(const uint2*)(y16 + (size_t)s1 * FDIM + 4 * fl);
            float4 f0 = half4_to_float4(u0);
            float4 f1 = half4_to_float4(u1);
            ax += f0.x + f1.x; ay += f0.y + f1.y;
            az += f0.z + f1.z; aw += f0.w + f1.w;
        }
        for (; j < m; j += 4) {                // tail: up to 4 edges, 1 load/lane
            int e = j + q;
            int se = __shfl(idx, (e < m) ? e : 0);
            uint2 u = *(const uint2*)(y16 + (size_t)se * FDIM + 4 * fl);
            if (e < m) {
                float4 f = half4_to_float4(u);
                ax += f.x; ay += f.y; az += f.z; aw += f.w;
            }
        }
    }
    // combine the 4 edge streams (lanes fl, fl+16, fl+32, fl+48)
    ax += __shfl_xor(ax, 16); ay += __shfl_xor(ay, 16);
    az += __shfl_xor(az, 16); aw += __shfl_xor(aw, 16);
    ax += __shfl_xor(ax, 32); ay += __shfl_xor(ay, 32);
    az += __shfl_xor(az, 32); aw += __shfl_xor(aw, 32);
    if (q == 0) {
        uint2 su = *(const uint2*)(y16 + (size_t)n * FDIM + 4 * fl);   // self loop
        float4 sf = half4_to_float4(su);
        float dv = dinv[n];
        float4 bb = ((const float4*)b)[fl];
        float ox = (ax + sf.x) * dv + bb.x;
        float oy = (ay + sf.y) * dv + bb.y;
        float oz = (az + sf.z) * dv + bb.z;
        float ow = (aw + sf.w) * dv + bb.w;
        if (RELU) {
            ox = fmaxf(ox, 0.f); oy = fmaxf(oy, 0.f);
            oz = fmaxf(oz, 0.f); ow = fmaxf(ow, 0.f);
        }
        if constexpr (sizeof(OUT_T) == 2) {
            union { __half2 h[2]; uint2 u; } cvt;
            cvt.h[0] = __floats2half2_rn(ox, oy);
            cvt.h[1] = __floats2half2_rn(oz, ow);
            *(uint2*)((__half*)out + (size_t)n * FDIM + 4 * fl) = cvt.u;
        } else {
            *(float4*)((float*)out + (size_t)n * FDIM + 4 * fl) = make_float4(ox, oy, oz, ow);
        }
    }
}

static inline size_t roundup256(size_t x) { return (x + 255) & ~(size_t)255; }

extern "C" void kernel_launch(void* const* d_in, const int* in_sizes, int n_in,
                              void* d_out, int out_size, void* d_ws, size_t ws_size,
                              hipStream_t stream) {
    const float* x  = (const float*)d_in[0];
    const void*  ei = d_in[1];
    const float* W1 = (const float*)d_in[2];
    const float* b1 = (const float*)d_in[3];
    const float* W2 = (const float*)d_in[4];
    const float* b2 = (const float*)d_in[5];
    float* out = (float*)d_out;

    int N = out_size / FDIM;                       // 100000
    int E = in_sizes[1] / 2;                       // 1200000
    int nseg = (N + SEG - 1) >> SEG_SHIFT;         // 196
    if (nseg > NSEGMAX) nseg = NSEGMAX;            // (N<=131072 assumed)
    int nblk_p = (E + PB_EDGES - 1) / PB_EDGES;    // 147

    // ws layout (256B-aligned slots)
    char* p = (char*)d_ws;
    float* dinv    = (float*)p;  p += roundup256((size_t)N * 4);
    __half* y16    = (__half*)p; p += roundup256((size_t)N * FDIM * 2);
    __half* h16    = (__half*)p; p += roundup256((size_t)N * FDIM * 2);
    int* gcount    = (int*)p;    p += (size_t)NSEGMAX * GSTRIDE * 4;   // 8 KB
    int* flag      = (int*)p;    p += 256;
    int* rowstart  = (int*)p;    p += roundup256((size_t)N * 4);
    int* degv      = (int*)p;    p += roundup256((size_t)N * 4);
    int* csr       = (int*)p;    p += (size_t)nseg * SCAP * 4;         // ~6.4 MB
    int2* parts    = (int2*)p;   p += (size_t)nseg * SCAP * sizeof(int2);  // ~12.8 MB

    hipMemsetAsync(gcount, 0, (size_t)NSEGMAX * GSTRIDE * 4, stream);

    // ---- graph prep: slab by segment, then per-segment counting sort ----
    detect_dtype_kernel<<<1, 256, 0, stream>>>((const int*)ei, 2048, flag);
    bucket_place<<<nblk_p, 256, 0, stream>>>(ei, flag, E, nseg, gcount, parts);
    place_sort<<<nseg, 256, 0, stream>>>(parts, gcount, csr, rowstart, degv, dinv, N);

    int gemm_grid = (N + 63) / 64;
    int gath_grid = (N + 3) / 4;

    // ---- layer 1: h = relu(GCNConv(x, W1, b1)) -> h16 (fp16) ----
    gemm_scale<float><<<gemm_grid, 256, 0, stream>>>(x, W1, dinv, y16, N);
    gather<true, __half><<<gath_grid, 256, 0, stream>>>(rowstart, degv, csr, y16, dinv, b1, h16, N);

    // ---- layer 2: out = GCNConv(h, W2, b2) -> fp32 d_out ----
    gemm_scale<__half><<<gemm_grid, 256, 0, stream>>>(h16, W2, dinv, y16, N);
    gather<false, float><<<gath_grid, 256, 0, stream>>>(rowstart, degv, csr, y16, dinv, b2, out, N);
}

// Round 12
// 178.958 us; speedup vs baseline: 6.2895x; 1.0606x over previous
//
#include <hip/hip_runtime.h>
#include <hip/hip_fp16.h>

#define FDIM 64
#define SEG 512               // nodes per segment
#define SEG_SHIFT 9
#define NSEGMAX 256
#define SCAP 8192             // slots per segment slab (mean ~6.1K, ~26 sigma headroom)
#define GSTRIDE 8             // ints between per-segment counters
#define PB_EDGES 8192         // edges per bucket_place block

// ---- detect int64 vs int32 edge_index + zero gcount (replaces 45us fill dispatch) ----
__global__ void detect_dtype_kernel(const int* ei, int nsamp, int* flag, int* gcount, int glen) {
    __shared__ int any_nz;
    if (threadIdx.x == 0) any_nz = 0;
    __syncthreads();
    int local = 0;
    for (int i = threadIdx.x; i < nsamp; i += blockDim.x) {
        if (ei[2 * i + 1] != 0) local = 1;   // odd dword: int64 high word (==0) vs real int32 index
    }
    if (local) atomicOr(&any_nz, 1);
    for (int i = threadIdx.x; i < glen; i += blockDim.x) gcount[i] = 0;
    __syncthreads();
    if (threadIdx.x == 0) flag[0] = (any_nz == 0) ? 1 : 0;   // 1 => int64
}

// ---- pass 1 over edges: slab (s,d) by segment d>>9. LDS histogram; one global
// atomic per (block,segment); NO per-edge global atomics. ----
__global__ __launch_bounds__(256) void bucket_place(const void* ei, const int* flag, int E,
                                                    int nseg,
                                                    int* __restrict__ gcount,
                                                    int2* __restrict__ parts) {
    __shared__ int lhist[NSEGMAX];
    __shared__ int lbase[NSEGMAX];
    __shared__ int loff[NSEGMAX];
    int is64 = flag[0];
    int t = threadIdx.x;
    const long long* q64 = (const long long*)ei;
    const int* q32 = (const int*)ei;
    int base = blockIdx.x * PB_EDGES;
    for (int i = t; i < nseg; i += 256) { lhist[i] = 0; loff[i] = 0; }
    __syncthreads();
    // phase A: local histogram (dst only)
    #pragma unroll 4
    for (int u = 0; u < PB_EDGES / 256; u++) {
        int i = base + u * 256 + t;
        if (i < E) {
            int d = is64 ? (int)q64[E + i] : q32[E + i];
            atomicAdd(&lhist[d >> SEG_SHIFT], 1);
        }
    }
    __syncthreads();
    // reserve: one global atomic per touched segment
    for (int i = t; i < nseg; i += 256)
        lbase[i] = (lhist[i] > 0) ? atomicAdd(&gcount[i * GSTRIDE], lhist[i]) : 0;
    __syncthreads();
    // phase B: re-read (cache-hot), rank via LDS rtn-atomic, write runs
    #pragma unroll 4
    for (int u = 0; u < PB_EDGES / 256; u++) {
        int i = base + u * 256 + t;
        if (i < E) {
            int s, d;
            if (is64) { s = (int)q64[i]; d = (int)q64[E + i]; }
            else      { s = q32[i];      d = q32[E + i]; }
            int bk = d >> SEG_SHIFT;
            int off = atomicAdd(&loff[bk], 1);
            int pos = lbase[bk] + off;
            if (pos < SCAP) parts[(size_t)bk * SCAP + pos] = make_int2(s, d);
        }
    }
}

// ---- pass 2: per-segment counting sort. One block per 512-node segment:
// LDS hist -> LDS scan -> rowstart/deg/dinv (coalesced) -> place src into csr
// via LDS cursor atomics. csr scatter stays inside a 32KB L2-resident window. ----
__global__ __launch_bounds__(256) void place_sort(const int2* __restrict__ parts,
                                                  const int* __restrict__ gcount,
                                                  int* __restrict__ csr,
                                                  int* __restrict__ rowstart,
                                                  int* __restrict__ degv,
                                                  float* __restrict__ dinv, int N) {
    __shared__ int hist[SEG];
    __shared__ int cur[SEG];
    __shared__ int A[256], B[256];
    int s = blockIdx.x;
    int t = threadIdx.x;
    int nbase = s << SEG_SHIFT;
    hist[t] = 0; hist[t + 256] = 0;
    __syncthreads();
    int cnt = gcount[s * GSTRIDE]; if (cnt > SCAP) cnt = SCAP;
    const int2* pg = parts + (size_t)s * SCAP;
    for (int j = t; j < cnt; j += 256) atomicAdd(&hist[pg[j].y & (SEG - 1)], 1);
    __syncthreads();
    // exclusive scan over 512 via pair-sum + 256-wide Hillis-Steele
    int p = hist[2 * t] + hist[2 * t + 1];
    A[t] = p; __syncthreads();
    int* in = A; int* out = B;
    for (int off = 1; off < 256; off <<= 1) {
        out[t] = in[t] + ((t >= off) ? in[t - off] : 0);
        __syncthreads();
        int* z = in; in = out; out = z;
    }
    int esc = (t == 0) ? 0 : in[t - 1];
    cur[2 * t] = esc;
    cur[2 * t + 1] = esc + hist[2 * t];
    __syncthreads();
    // emit per-node metadata (coalesced)
    for (int i = t; i < SEG; i += 256) {
        int n = nbase + i;
        if (n < N) {
            rowstart[n] = s * SCAP + cur[i];
            degv[n] = hist[i];
            dinv[n] = rsqrtf((float)(hist[i] + 1));
        }
    }
    __syncthreads();
    // place: LDS cursor atomics only
    for (int j = t; j < cnt; j += 256) {
        int2 e = pg[j];
        int r = e.y & (SEG - 1);
        int off = atomicAdd(&cur[r], 1);
        csr[(size_t)s * SCAP + off] = e.x;
    }
}

// ---- y16[n,:] = half((x[n,:] @ W) * dinv[n]) — LDS-tiled 64x64 ----
template <typename TIN>
__global__ __launch_bounds__(256, 4) void gemm_scale(const TIN* __restrict__ x,
                                                     const float* __restrict__ W,
                                                     const float* __restrict__ dinv,
                                                     __half* __restrict__ y16, int N) {
    __shared__ float Xl[64 * 68];   // pad to 68 to break bank aliasing
    __shared__ float Wl[64 * 64];
    int t = threadIdx.x;
    int nbase = blockIdx.x * 64;
    for (int i = t; i < 1024; i += 256) {
        ((float4*)Wl)[i] = ((const float4*)W)[i];
    }
    for (int i = t; i < 1024; i += 256) {
        int flat = i * 4;
        int n = flat >> 6, k = flat & 63;
        int g = nbase + n;
        float4 v;
        if (g < N) {
            if constexpr (sizeof(TIN) == 2) {
                const __half2* hp = (const __half2*)((const __half*)x + (size_t)g * FDIM + k);
                float2 a = __half22float2(hp[0]);
                float2 c = __half22float2(hp[1]);
                v = make_float4(a.x, a.y, c.x, c.y);
            } else {
                v = *(const float4*)((const float*)x + (size_t)g * FDIM + k);
            }
        } else {
            v = make_float4(0.f, 0.f, 0.f, 0.f);
        }
        *(float4*)&Xl[n * 68 + k] = v;
    }
    __syncthreads();

    int fr = t & 15;    // feature group: feats fr*4..fr*4+3
    int ng = t >> 4;    // node group:    nodes ng*4..ng*4+3
    float acc[4][4] = {{0.f}};
    #pragma unroll 4
    for (int kc = 0; kc < 16; kc++) {
        float4 xa[4], wa[4];
        #pragma unroll
        for (int i = 0; i < 4; i++) xa[i] = *(float4*)&Xl[(ng * 4 + i) * 68 + kc * 4];
        #pragma unroll
        for (int j = 0; j < 4; j++) wa[j] = *(float4*)&Wl[(kc * 4 + j) * 64 + fr * 4];
        #pragma unroll
        for (int i = 0; i < 4; i++) {
            acc[i][0] += xa[i].x * wa[0].x + xa[i].y * wa[1].x + xa[i].z * wa[2].x + xa[i].w * wa[3].x;
            acc[i][1] += xa[i].x * wa[0].y + xa[i].y * wa[1].y + xa[i].z * wa[2].y + xa[i].w * wa[3].y;
            acc[i][2] += xa[i].x * wa[0].z + xa[i].y * wa[1].z + xa[i].z * wa[2].z + xa[i].w * wa[3].z;
            acc[i][3] += xa[i].x * wa[0].w + xa[i].y * wa[1].w + xa[i].z * wa[2].w + xa[i].w * wa[3].w;
        }
    }
    #pragma unroll
    for (int i = 0; i < 4; i++) {
        int g = nbase + ng * 4 + i;
        if (g < N) {
            float dv = dinv[g];
            __half2 ha = __floats2half2_rn(acc[i][0] * dv, acc[i][1] * dv);
            __half2 hb = __floats2half2_rn(acc[i][2] * dv, acc[i][3] * dv);
            union { __half2 h[2]; uint2 u; } cvt;
            cvt.h[0] = ha; cvt.h[1] = hb;
            *(uint2*)(y16 + (size_t)g * FDIM + fr * 4) = cvt.u;
        }
    }
}

__device__ __forceinline__ float4 half4_to_float4(uint2 u) {
    float2 a = __half22float2(*(__half2*)&u.x);
    float2 b = __half22float2(*(__half2*)&u.y);
    return make_float4(a.x, a.y, b.x, b.y);
}

// ---- gather: out[n,:] = dinv[n]*(y[n,:] + sum_bucket y[src,:]) + b (+ReLU) ----
// 4 edge streams x 16-lane rows: lane = 16*q + fl; each lane holds feats 4fl..4fl+3
// (uint2 = 4 halves). Streams combined via shfl_xor(16), shfl_xor(32).
template <bool RELU, typename OUT_T>
__global__ __launch_bounds__(256) void gather(const int* __restrict__ rowstart,
                                              const int* __restrict__ degv,
                                              const int* __restrict__ csr,
                                              const __half* __restrict__ y16,
                                              const float* __restrict__ dinv,
                                              const float* __restrict__ b,
                                              OUT_T* __restrict__ out, int N) {
    int lane = threadIdx.x & 63;
    int n = blockIdx.x * 4 + (threadIdx.x >> 6);
    if (n >= N) return;
    int q = lane >> 4;       // edge stream 0..3
    int fl = lane & 15;      // feature quad: feats 4fl..4fl+3
    int start = rowstart[n];
    int end = start + degv[n];
    // hoist self-loop row load: independent of edge loop, overlaps with it
    uint2 su = make_uint2(0u, 0u);
    if (q == 0) su = *(const uint2*)(y16 + (size_t)n * FDIM + 4 * fl);
    float ax = 0.f, ay = 0.f, az = 0.f, aw = 0.f;
    for (int base = start; base < end; base += 64) {
        int m = end - base; if (m > 64) m = 64;
        int idx = (lane < m) ? csr[base + lane] : 0;
        int j = 0;
        for (; j + 7 < m; j += 8) {            // 8 edges via 2 row-loads/lane
            int s0 = __shfl(idx, j + q);
            int s1 = __shfl(idx, j + 4 + q);
            uint2 u0 = *(const uint2*)(y16 + (size_t)s0 * FDIM + 4 * fl);
            uint2 u1 = *(const uint2*)(y16 + (size_t)s1 * FDIM + 4 * fl);
            float4 f0 = half4_to_float4(u0);
            float4 f1 = half4_to_float4(u1);
            ax += f0.x + f1.x; ay += f0.y + f1.y;
            az += f0.z + f1.z; aw += f0.w + f1.w;
        }
        for (; j < m; j += 4) {                // tail: up to 4 edges, 1 load/lane
            int e = j + q;
            int se = __shfl(idx, (e < m) ? e : 0);
            uint2 u = *(const uint2*)(y16 + (size_t)se * FDIM + 4 * fl);
            if (e < m) {
                float4 f = half4_to_float4(u);
                ax += f.x; ay += f.y; az += f.z; aw += f.w;
            }
        }
    }
    // combine the 4 edge streams (lanes fl, fl+16, fl+32, fl+48)
    ax += __shfl_xor(ax, 16); ay += __shfl_xor(ay, 16);
    az += __shfl_xor(az, 16); aw += __shfl_xor(aw, 16);
    ax += __shfl_xor(ax, 32); ay += __shfl_xor(ay, 32);
    az += __shfl_xor(az, 32); aw += __shfl_xor(aw, 32);
    if (q == 0) {
        float4 sf = half4_to_float4(su);
        float dv = dinv[n];
        float4 bb = ((const float4*)b)[fl];
        float ox = (ax + sf.x) * dv + bb.x;
        float oy = (ay + sf.y) * dv + bb.y;
        float oz = (az + sf.z) * dv + bb.z;
        float ow = (aw + sf.w) * dv + bb.w;
        if (RELU) {
            ox = fmaxf(ox, 0.f); oy = fmaxf(oy, 0.f);
            oz = fmaxf(oz, 0.f); ow = fmaxf(ow, 0.f);
        }
        if constexpr (sizeof(OUT_T) == 2) {
            union { __half2 h[2]; uint2 u; } cvt;
            cvt.h[0] = __floats2half2_rn(ox, oy);
            cvt.h[1] = __floats2half2_rn(oz, ow);
            *(uint2*)((__half*)out + (size_t)n * FDIM + 4 * fl) = cvt.u;
        } else {
            *(float4*)((float*)out + (size_t)n * FDIM + 4 * fl) = make_float4(ox, oy, oz, ow);
        }
    }
}

static inline size_t roundup256(size_t x) { return (x + 255) & ~(size_t)255; }

extern "C" void kernel_launch(void* const* d_in, const int* in_sizes, int n_in,
                              void* d_out, int out_size, void* d_ws, size_t ws_size,
                              hipStream_t stream) {
    const float* x  = (const float*)d_in[0];
    const void*  ei = d_in[1];
    const float* W1 = (const float*)d_in[2];
    const float* b1 = (const float*)d_in[3];
    const float* W2 = (const float*)d_in[4];
    const float* b2 = (const float*)d_in[5];
    float* out = (float*)d_out;

    int N = out_size / FDIM;                       // 100000
    int E = in_sizes[1] / 2;                       // 1200000
    int nseg = (N + SEG - 1) >> SEG_SHIFT;         // 196
    if (nseg > NSEGMAX) nseg = NSEGMAX;            // (N<=131072 assumed)
    int nblk_p = (E + PB_EDGES - 1) / PB_EDGES;    // 147

    // ws layout (256B-aligned slots)
    char* p = (char*)d_ws;
    float* dinv    = (float*)p;  p += roundup256((size_t)N * 4);
    __half* y16    = (__half*)p; p += roundup256((size_t)N * FDIM * 2);
    __half* h16    = (__half*)p; p += roundup256((size_t)N * FDIM * 2);
    int* gcount    = (int*)p;    p += (size_t)NSEGMAX * GSTRIDE * 4;   // 8 KB
    int* flag      = (int*)p;    p += 256;
    int* rowstart  = (int*)p;    p += roundup256((size_t)N * 4);
    int* degv      = (int*)p;    p += roundup256((size_t)N * 4);
    int* csr       = (int*)p;    p += (size_t)nseg * SCAP * 4;         // ~6.4 MB
    int2* parts    = (int2*)p;   p += (size_t)nseg * SCAP * sizeof(int2);  // ~12.8 MB

    // ---- graph prep: detect dtype + zero gcount, slab by segment, counting sort ----
    detect_dtype_kernel<<<1, 256, 0, stream>>>((const int*)ei, 2048, flag,
                                               gcount, NSEGMAX * GSTRIDE);
    bucket_place<<<nblk_p, 256, 0, stream>>>(ei, flag, E, nseg, gcount, parts);
    place_sort<<<nseg, 256, 0, stream>>>(parts, gcount, csr, rowstart, degv, dinv, N);

    int gemm_grid = (N + 63) / 64;
    int gath_grid = (N + 3) / 4;

    // ---- layer 1: h = relu(GCNConv(x, W1, b1)) -> h16 (fp16) ----
    gemm_scale<float><<<gemm_grid, 256, 0, stream>>>(x, W1, dinv, y16, N);
    gather<true, __half><<<gath_grid, 256, 0, stream>>>(rowstart, degv, csr, y16, dinv, b1, h16, N);

    // ---- layer 2: out = GCNConv(h, W2, b2) -> fp32 d_out ----
    gemm_scale<__half><<<gemm_grid, 256, 0, stream>>>(h16, W2, dinv, y16, N);
    gather<false, float><<<gath_grid, 256, 0, stream>>>(rowstart, degv, csr, y16, dinv, b2, out, N);
}

// Round 13
// 175.413 us; speedup vs baseline: 6.4166x; 1.0202x over previous
//
#include <hip/hip_runtime.h>
#include <hip/hip_fp16.h>

#define FDIM 64
#define SEG 512               // nodes per segment
#define SEG_SHIFT 9
#define NSEGMAX 256
#define SCAP 8192             // slots per segment slab (mean ~6.1K, ~26 sigma headroom)
#define GSTRIDE 8             // ints between per-segment counters
#define PB_EDGES 8192         // edges per bucket_place block

// ---- detect int64 vs int32 edge_index + zero gcount ----
__global__ void detect_dtype_kernel(const int* ei, int nsamp, int* flag, int* gcount, int glen) {
    __shared__ int any_nz;
    if (threadIdx.x == 0) any_nz = 0;
    __syncthreads();
    int local = 0;
    for (int i = threadIdx.x; i < nsamp; i += blockDim.x) {
        if (ei[2 * i + 1] != 0) local = 1;   // odd dword: int64 high word (==0) vs real int32 index
    }
    if (local) atomicOr(&any_nz, 1);
    for (int i = threadIdx.x; i < glen; i += blockDim.x) gcount[i] = 0;
    __syncthreads();
    if (threadIdx.x == 0) flag[0] = (any_nz == 0) ? 1 : 0;   // 1 => int64
}

// ---- pass 1 over edges: slab (s,d) by segment d>>9. LDS histogram; one global
// atomic per (block,segment); NO per-edge global atomics. ----
__global__ __launch_bounds__(256) void bucket_place(const void* ei, const int* flag, int E,
                                                    int nseg,
                                                    int* __restrict__ gcount,
                                                    int2* __restrict__ parts) {
    __shared__ int lhist[NSEGMAX];
    __shared__ int lbase[NSEGMAX];
    __shared__ int loff[NSEGMAX];
    int is64 = flag[0];
    int t = threadIdx.x;
    const long long* q64 = (const long long*)ei;
    const int* q32 = (const int*)ei;
    int base = blockIdx.x * PB_EDGES;
    for (int i = t; i < nseg; i += 256) { lhist[i] = 0; loff[i] = 0; }
    __syncthreads();
    // phase A: local histogram (dst only)
    #pragma unroll 4
    for (int u = 0; u < PB_EDGES / 256; u++) {
        int i = base + u * 256 + t;
        if (i < E) {
            int d = is64 ? (int)q64[E + i] : q32[E + i];
            atomicAdd(&lhist[d >> SEG_SHIFT], 1);
        }
    }
    __syncthreads();
    // reserve: one global atomic per touched segment
    for (int i = t; i < nseg; i += 256)
        lbase[i] = (lhist[i] > 0) ? atomicAdd(&gcount[i * GSTRIDE], lhist[i]) : 0;
    __syncthreads();
    // phase B: re-read (cache-hot), rank via LDS rtn-atomic, write runs
    #pragma unroll 4
    for (int u = 0; u < PB_EDGES / 256; u++) {
        int i = base + u * 256 + t;
        if (i < E) {
            int s, d;
            if (is64) { s = (int)q64[i]; d = (int)q64[E + i]; }
            else      { s = q32[i];      d = q32[E + i]; }
            int bk = d >> SEG_SHIFT;
            int off = atomicAdd(&loff[bk], 1);
            int pos = lbase[bk] + off;
            if (pos < SCAP) parts[(size_t)bk * SCAP + pos] = make_int2(s, d);
        }
    }
}

// ---- pass 2: per-segment counting sort. One block per 512-node segment:
// LDS hist -> LDS scan -> rowstart/deg/dinv (coalesced) -> place src into csr
// via LDS cursor atomics. csr scatter stays inside a 32KB L2-resident window. ----
__global__ __launch_bounds__(256) void place_sort(const int2* __restrict__ parts,
                                                  const int* __restrict__ gcount,
                                                  int* __restrict__ csr,
                                                  int* __restrict__ rowstart,
                                                  int* __restrict__ degv,
                                                  float* __restrict__ dinv, int N) {
    __shared__ int hist[SEG];
    __shared__ int cur[SEG];
    __shared__ int A[256], B[256];
    int s = blockIdx.x;
    int t = threadIdx.x;
    int nbase = s << SEG_SHIFT;
    hist[t] = 0; hist[t + 256] = 0;
    __syncthreads();
    int cnt = gcount[s * GSTRIDE]; if (cnt > SCAP) cnt = SCAP;
    const int2* pg = parts + (size_t)s * SCAP;
    for (int j = t; j < cnt; j += 256) atomicAdd(&hist[pg[j].y & (SEG - 1)], 1);
    __syncthreads();
    // exclusive scan over 512 via pair-sum + 256-wide Hillis-Steele
    int p = hist[2 * t] + hist[2 * t + 1];
    A[t] = p; __syncthreads();
    int* in = A; int* out = B;
    for (int off = 1; off < 256; off <<= 1) {
        out[t] = in[t] + ((t >= off) ? in[t - off] : 0);
        __syncthreads();
        int* z = in; in = out; out = z;
    }
    int esc = (t == 0) ? 0 : in[t - 1];
    cur[2 * t] = esc;
    cur[2 * t + 1] = esc + hist[2 * t];
    __syncthreads();
    // emit per-node metadata (coalesced)
    for (int i = t; i < SEG; i += 256) {
        int n = nbase + i;
        if (n < N) {
            rowstart[n] = s * SCAP + cur[i];
            degv[n] = hist[i];
            dinv[n] = rsqrtf((float)(hist[i] + 1));
        }
    }
    __syncthreads();
    // place: LDS cursor atomics only
    for (int j = t; j < cnt; j += 256) {
        int2 e = pg[j];
        int r = e.y & (SEG - 1);
        int off = atomicAdd(&cur[r], 1);
        csr[(size_t)s * SCAP + off] = e.x;
    }
}

// ---- y16[n,:] = half((x[n,:] @ W) * dinv[n]) — LDS-tiled 64x64 ----
template <typename TIN>
__global__ __launch_bounds__(256, 4) void gemm_scale(const TIN* __restrict__ x,
                                                     const float* __restrict__ W,
                                                     const float* __restrict__ dinv,
                                                     __half* __restrict__ y16, int N) {
    __shared__ float Xl[64 * 68];   // pad to 68 to break bank aliasing
    __shared__ float Wl[64 * 64];
    int t = threadIdx.x;
    int nbase = blockIdx.x * 64;
    for (int i = t; i < 1024; i += 256) {
        ((float4*)Wl)[i] = ((const float4*)W)[i];
    }
    for (int i = t; i < 1024; i += 256) {
        int flat = i * 4;
        int n = flat >> 6, k = flat & 63;
        int g = nbase + n;
        float4 v;
        if (g < N) {
            if constexpr (sizeof(TIN) == 2) {
                const __half2* hp = (const __half2*)((const __half*)x + (size_t)g * FDIM + k);
                float2 a = __half22float2(hp[0]);
                float2 c = __half22float2(hp[1]);
                v = make_float4(a.x, a.y, c.x, c.y);
            } else {
                v = *(const float4*)((const float*)x + (size_t)g * FDIM + k);
            }
        } else {
            v = make_float4(0.f, 0.f, 0.f, 0.f);
        }
        *(float4*)&Xl[n * 68 + k] = v;
    }
    __syncthreads();

    int fr = t & 15;    // feature group: feats fr*4..fr*4+3
    int ng = t >> 4;    // node group:    nodes ng*4..ng*4+3
    float acc[4][4] = {{0.f}};
    #pragma unroll 4
    for (int kc = 0; kc < 16; kc++) {
        float4 xa[4], wa[4];
        #pragma unroll
        for (int i = 0; i < 4; i++) xa[i] = *(float4*)&Xl[(ng * 4 + i) * 68 + kc * 4];
        #pragma unroll
        for (int j = 0; j < 4; j++) wa[j] = *(float4*)&Wl[(kc * 4 + j) * 64 + fr * 4];
        #pragma unroll
        for (int i = 0; i < 4; i++) {
            acc[i][0] += xa[i].x * wa[0].x + xa[i].y * wa[1].x + xa[i].z * wa[2].x + xa[i].w * wa[3].x;
            acc[i][1] += xa[i].x * wa[0].y + xa[i].y * wa[1].y + xa[i].z * wa[2].y + xa[i].w * wa[3].y;
            acc[i][2] += xa[i].x * wa[0].z + xa[i].y * wa[1].z + xa[i].z * wa[2].z + xa[i].w * wa[3].z;
            acc[i][3] += xa[i].x * wa[0].w + xa[i].y * wa[1].w + xa[i].z * wa[2].w + xa[i].w * wa[3].w;
        }
    }
    #pragma unroll
    for (int i = 0; i < 4; i++) {
        int g = nbase + ng * 4 + i;
        if (g < N) {
            float dv = dinv[g];
            __half2 ha = __floats2half2_rn(acc[i][0] * dv, acc[i][1] * dv);
            __half2 hb = __floats2half2_rn(acc[i][2] * dv, acc[i][3] * dv);
            union { __half2 h[2]; uint2 u; } cvt;
            cvt.h[0] = ha; cvt.h[1] = hb;
            *(uint2*)(y16 + (size_t)g * FDIM + fr * 4) = cvt.u;
        }
    }
}

__device__ __forceinline__ float4 half4_to_float4(uint2 u) {
    float2 a = __half22float2(*(__half2*)&u.x);
    float2 b = __half22float2(*(__half2*)&u.y);
    return make_float4(a.x, a.y, b.x, b.y);
}

// ---- gather: out[n,:] = dinv[n]*(y[n,:] + sum_bucket y[src,:]) + b (+ReLU) ----
// 4 edge streams x 16-lane rows. Inner loop: 16-edge group = 4 INDEPENDENT
// row-loads issued back-to-back per lane (clamped shfl indices, masked adds)
// so every node (even deg<16, the common case) has 4 loads in flight.
template <bool RELU, typename OUT_T>
__global__ __launch_bounds__(256) void gather(const int* __restrict__ rowstart,
                                              const int* __restrict__ degv,
                                              const int* __restrict__ csr,
                                              const __half* __restrict__ y16,
                                              const float* __restrict__ dinv,
                                              const float* __restrict__ b,
                                              OUT_T* __restrict__ out, int N) {
    int lane = threadIdx.x & 63;
    int n = blockIdx.x * 4 + (threadIdx.x >> 6);
    if (n >= N) return;
    int q = lane >> 4;       // edge stream 0..3
    int fl = lane & 15;      // feature quad: feats 4fl..4fl+3
    int start = rowstart[n];
    int end = start + degv[n];
    // hoist self-loop row load: independent of edge loop, overlaps with it
    uint2 su = make_uint2(0u, 0u);
    if (q == 0) su = *(const uint2*)(y16 + (size_t)n * FDIM + 4 * fl);
    float ax = 0.f, ay = 0.f, az = 0.f, aw = 0.f;
    for (int base = start; base < end; base += 64) {
        int m = end - base; if (m > 64) m = 64;
        int idx = (lane < m) ? csr[base + lane] : 0;
        for (int j = 0; j < m; j += 16) {
            int e0 = j + q, e1 = j + 4 + q, e2 = j + 8 + q, e3 = j + 12 + q;
            int s0 = __shfl(idx, (e0 < m) ? e0 : (m - 1));
            int s1 = __shfl(idx, (e1 < m) ? e1 : (m - 1));
            int s2 = __shfl(idx, (e2 < m) ? e2 : (m - 1));
            int s3 = __shfl(idx, (e3 < m) ? e3 : (m - 1));
            uint2 u0 = *(const uint2*)(y16 + (size_t)s0 * FDIM + 4 * fl);
            uint2 u1 = *(const uint2*)(y16 + (size_t)s1 * FDIM + 4 * fl);
            uint2 u2 = *(const uint2*)(y16 + (size_t)s2 * FDIM + 4 * fl);
            uint2 u3 = *(const uint2*)(y16 + (size_t)s3 * FDIM + 4 * fl);
            if (e0 < m) { float4 f = half4_to_float4(u0); ax += f.x; ay += f.y; az += f.z; aw += f.w; }
            if (e1 < m) { float4 f = half4_to_float4(u1); ax += f.x; ay += f.y; az += f.z; aw += f.w; }
            if (e2 < m) { float4 f = half4_to_float4(u2); ax += f.x; ay += f.y; az += f.z; aw += f.w; }
            if (e3 < m) { float4 f = half4_to_float4(u3); ax += f.x; ay += f.y; az += f.z; aw += f.w; }
        }
    }
    // combine the 4 edge streams (lanes fl, fl+16, fl+32, fl+48)
    ax += __shfl_xor(ax, 16); ay += __shfl_xor(ay, 16);
    az += __shfl_xor(az, 16); aw += __shfl_xor(aw, 16);
    ax += __shfl_xor(ax, 32); ay += __shfl_xor(ay, 32);
    az += __shfl_xor(az, 32); aw += __shfl_xor(aw, 32);
    if (q == 0) {
        float4 sf = half4_to_float4(su);
        float dv = dinv[n];
        float4 bb = ((const float4*)b)[fl];
        float ox = (ax + sf.x) * dv + bb.x;
        float oy = (ay + sf.y) * dv + bb.y;
        float oz = (az + sf.z) * dv + bb.z;
        float ow = (aw + sf.w) * dv + bb.w;
        if (RELU) {
            ox = fmaxf(ox, 0.f); oy = fmaxf(oy, 0.f);
            oz = fmaxf(oz, 0.f); ow = fmaxf(ow, 0.f);
        }
        if constexpr (sizeof(OUT_T) == 2) {
            union { __half2 h[2]; uint2 u; } cvt;
            cvt.h[0] = __floats2half2_rn(ox, oy);
            cvt.h[1] = __floats2half2_rn(oz, ow);
            *(uint2*)((__half*)out + (size_t)n * FDIM + 4 * fl) = cvt.u;
        } else {
            *(float4*)((float*)out + (size_t)n * FDIM + 4 * fl) = make_float4(ox, oy, oz, ow);
        }
    }
}

static inline size_t roundup256(size_t x) { return (x + 255) & ~(size_t)255; }

extern "C" void kernel_launch(void* const* d_in, const int* in_sizes, int n_in,
                              void* d_out, int out_size, void* d_ws, size_t ws_size,
                              hipStream_t stream) {
    const float* x  = (const float*)d_in[0];
    const void*  ei = d_in[1];
    const float* W1 = (const float*)d_in[2];
    const float* b1 = (const float*)d_in[3];
    const float* W2 = (const float*)d_in[4];
    const float* b2 = (const float*)d_in[5];
    float* out = (float*)d_out;

    int N = out_size / FDIM;                       // 100000
    int E = in_sizes[1] / 2;                       // 1200000
    int nseg = (N + SEG - 1) >> SEG_SHIFT;         // 196
    if (nseg > NSEGMAX) nseg = NSEGMAX;            // (N<=131072 assumed)
    int nblk_p = (E + PB_EDGES - 1) / PB_EDGES;    // 147

    // ws layout (256B-aligned slots)
    char* p = (char*)d_ws;
    float* dinv    = (float*)p;  p += roundup256((size_t)N * 4);
    __half* y16    = (__half*)p; p += roundup256((size_t)N * FDIM * 2);
    __half* h16    = (__half*)p; p += roundup256((size_t)N * FDIM * 2);
    int* gcount    = (int*)p;    p += (size_t)NSEGMAX * GSTRIDE * 4;   // 8 KB
    int* flag      = (int*)p;    p += 256;
    int* rowstart  = (int*)p;    p += roundup256((size_t)N * 4);
    int* degv      = (int*)p;    p += roundup256((size_t)N * 4);
    int* csr       = (int*)p;    p += (size_t)nseg * SCAP * 4;         // ~6.4 MB
    int2* parts    = (int2*)p;   p += (size_t)nseg * SCAP * sizeof(int2);  // ~12.8 MB

    // ---- graph prep: detect dtype + zero gcount, slab by segment, counting sort ----
    detect_dtype_kernel<<<1, 256, 0, stream>>>((const int*)ei, 2048, flag,
                                               gcount, NSEGMAX * GSTRIDE);
    bucket_place<<<nblk_p, 256, 0, stream>>>(ei, flag, E, nseg, gcount, parts);
    place_sort<<<nseg, 256, 0, stream>>>(parts, gcount, csr, rowstart, degv, dinv, N);

    int gemm_grid = (N + 63) / 64;
    int gath_grid = (N + 3) / 4;

    // ---- layer 1: h = relu(GCNConv(x, W1, b1)) -> h16 (fp16) ----
    gemm_scale<float><<<gemm_grid, 256, 0, stream>>>(x, W1, dinv, y16, N);
    gather<true, __half><<<gath_grid, 256, 0, stream>>>(rowstart, degv, csr, y16, dinv, b1, h16, N);

    // ---- layer 2: out = GCNConv(h, W2, b2) -> fp32 d_out ----
    gemm_scale<__half><<<gemm_grid, 256, 0, stream>>>(h16, W2, dinv, y16, N);
    gather<false, float><<<gath_grid, 256, 0, stream>>>(rowstart, degv, csr, y16, dinv, b2, out, N);
}

// Round 14
// 156.109 us; speedup vs baseline: 7.2100x; 1.1237x over previous
//
#include <hip/hip_runtime.h>
#include <hip/hip_fp16.h>

#define FDIM 64
#define SEG 512               // nodes per segment
#define SEG_SHIFT 9
#define NSEGMAX 256
#define SCAP 8192             // slots per segment slab (mean ~6.1K, ~26 sigma headroom)
#define GSTRIDE 8             // ints between per-segment counters
#define PB_EDGES 4096         // edges per bucket_place block (293 blocks > 256 CUs)

typedef _Float16 h2_t __attribute__((ext_vector_type(2)));

// ---- detect int64 vs int32 edge_index + zero gcount ----
__global__ void detect_dtype_kernel(const int* ei, int nsamp, int* flag, int* gcount, int glen) {
    __shared__ int any_nz;
    if (threadIdx.x == 0) any_nz = 0;
    __syncthreads();
    int local = 0;
    for (int i = threadIdx.x; i < nsamp; i += blockDim.x) {
        if (ei[2 * i + 1] != 0) local = 1;   // odd dword: int64 high word (==0) vs real int32 index
    }
    if (local) atomicOr(&any_nz, 1);
    for (int i = threadIdx.x; i < glen; i += blockDim.x) gcount[i] = 0;
    __syncthreads();
    if (threadIdx.x == 0) flag[0] = (any_nz == 0) ? 1 : 0;   // 1 => int64
}

// ---- pass 1 over edges: slab (s,d) by segment d>>9. LDS histogram; one global
// atomic per (block,segment); NO per-edge global atomics. ----
__global__ __launch_bounds__(256) void bucket_place(const void* ei, const int* flag, int E,
                                                    int nseg,
                                                    int* __restrict__ gcount,
                                                    int2* __restrict__ parts) {
    __shared__ int lhist[NSEGMAX];
    __shared__ int lbase[NSEGMAX];
    __shared__ int loff[NSEGMAX];
    int is64 = flag[0];
    int t = threadIdx.x;
    const long long* q64 = (const long long*)ei;
    const int* q32 = (const int*)ei;
    int base = blockIdx.x * PB_EDGES;
    for (int i = t; i < nseg; i += 256) { lhist[i] = 0; loff[i] = 0; }
    __syncthreads();
    // phase A: local histogram (dst only)
    #pragma unroll 4
    for (int u = 0; u < PB_EDGES / 256; u++) {
        int i = base + u * 256 + t;
        if (i < E) {
            int d = is64 ? (int)q64[E + i] : q32[E + i];
            atomicAdd(&lhist[d >> SEG_SHIFT], 1);
        }
    }
    __syncthreads();
    // reserve: one global atomic per touched segment
    for (int i = t; i < nseg; i += 256)
        lbase[i] = (lhist[i] > 0) ? atomicAdd(&gcount[i * GSTRIDE], lhist[i]) : 0;
    __syncthreads();
    // phase B: re-read (cache-hot), rank via LDS rtn-atomic, write runs
    #pragma unroll 4
    for (int u = 0; u < PB_EDGES / 256; u++) {
        int i = base + u * 256 + t;
        if (i < E) {
            int s, d;
            if (is64) { s = (int)q64[i]; d = (int)q64[E + i]; }
            else      { s = q32[i];      d = q32[E + i]; }
            int bk = d >> SEG_SHIFT;
            int off = atomicAdd(&loff[bk], 1);
            int pos = lbase[bk] + off;
            if (pos < SCAP) parts[(size_t)bk * SCAP + pos] = make_int2(s, d);
        }
    }
}

// ---- pass 2: per-segment counting sort. One block per 512-node segment:
// LDS hist -> LDS scan -> rowstart/deg/dinv (coalesced) -> place src into csr
// via LDS cursor atomics. csr scatter stays inside a 32KB L2-resident window. ----
__global__ __launch_bounds__(256) void place_sort(const int2* __restrict__ parts,
                                                  const int* __restrict__ gcount,
                                                  int* __restrict__ csr,
                                                  int* __restrict__ rowstart,
                                                  int* __restrict__ degv,
                                                  float* __restrict__ dinv, int N) {
    __shared__ int hist[SEG];
    __shared__ int cur[SEG];
    __shared__ int A[256], B[256];
    int s = blockIdx.x;
    int t = threadIdx.x;
    int nbase = s << SEG_SHIFT;
    hist[t] = 0; hist[t + 256] = 0;
    __syncthreads();
    int cnt = gcount[s * GSTRIDE]; if (cnt > SCAP) cnt = SCAP;
    const int2* pg = parts + (size_t)s * SCAP;
    for (int j = t; j < cnt; j += 256) atomicAdd(&hist[pg[j].y & (SEG - 1)], 1);
    __syncthreads();
    // exclusive scan over 512 via pair-sum + 256-wide Hillis-Steele
    int p = hist[2 * t] + hist[2 * t + 1];
    A[t] = p; __syncthreads();
    int* in = A; int* out = B;
    for (int off = 1; off < 256; off <<= 1) {
        out[t] = in[t] + ((t >= off) ? in[t - off] : 0);
        __syncthreads();
        int* z = in; in = out; out = z;
    }
    int esc = (t == 0) ? 0 : in[t - 1];
    cur[2 * t] = esc;
    cur[2 * t + 1] = esc + hist[2 * t];
    __syncthreads();
    // emit per-node metadata (coalesced)
    for (int i = t; i < SEG; i += 256) {
        int n = nbase + i;
        if (n < N) {
            rowstart[n] = s * SCAP + cur[i];
            degv[n] = hist[i];
            dinv[n] = rsqrtf((float)(hist[i] + 1));
        }
    }
    __syncthreads();
    // place: LDS cursor atomics only
    for (int j = t; j < cnt; j += 256) {
        int2 e = pg[j];
        int r = e.y & (SEG - 1);
        int off = atomicAdd(&cur[r], 1);
        csr[(size_t)s * SCAP + off] = e.x;
    }
}

// ---- y16[n,:] = half((x[n,:] @ W) * dinv[n]) — LDS-tiled 64x64, fp16 dot2 ----
// X and W pre-packed as half2 over k in LDS; v_dot2_f32_f16 accumulates in fp32:
// half the VALU ops and half the LDS of the fp32 version.
template <typename TIN>
__global__ __launch_bounds__(256, 4) void gemm_scale(const TIN* __restrict__ x,
                                                     const float* __restrict__ W,
                                                     const float* __restrict__ dinv,
                                                     __half* __restrict__ y16, int N) {
    __shared__ h2_t Xl[64 * 34];    // [node][k2], pad 34 to break bank aliasing
    __shared__ h2_t Wl[32 * 64];    // [k2][feat] = (W[2k2][f], W[2k2+1][f])
    int t = threadIdx.x;
    int nbase = blockIdx.x * 64;
    // stage W packed over k-pairs (coalesced over f)
    for (int i = t; i < 2048; i += 256) {
        int k2 = i >> 6, f = i & 63;
        float w0 = W[(2 * k2) * FDIM + f];
        float w1 = W[(2 * k2 + 1) * FDIM + f];
        h2_t pk; pk.x = (_Float16)w0; pk.y = (_Float16)w1;
        Wl[i] = pk;
    }
    // stage X tile as half2 pairs
    for (int i = t; i < 1024; i += 256) {
        int flat = i * 4;
        int n = flat >> 6, k = flat & 63;
        int g = nbase + n;
        h2_t a, c;
        if (g < N) {
            if constexpr (sizeof(TIN) == 2) {
                uint2 u = *(const uint2*)((const __half*)x + (size_t)g * FDIM + k);
                a = *(h2_t*)&u.x; c = *(h2_t*)&u.y;
            } else {
                float4 v = *(const float4*)((const float*)x + (size_t)g * FDIM + k);
                a.x = (_Float16)v.x; a.y = (_Float16)v.y;
                c.x = (_Float16)v.z; c.y = (_Float16)v.w;
            }
        } else {
            a.x = (_Float16)0.f; a.y = (_Float16)0.f; c = a;
        }
        Xl[n * 34 + (k >> 1)] = a;
        Xl[n * 34 + (k >> 1) + 1] = c;
    }
    __syncthreads();

    int fr = t & 15;    // feature group: feats fr*4..fr*4+3
    int ng = t >> 4;    // node group:    nodes ng*4..ng*4+3
    float acc[4][4] = {{0.f}};
    #pragma unroll 8
    for (int k2 = 0; k2 < 32; k2++) {
        h2_t xa[4], wa[4];
        #pragma unroll
        for (int i = 0; i < 4; i++) xa[i] = Xl[(ng * 4 + i) * 34 + k2];
        #pragma unroll
        for (int j = 0; j < 4; j++) wa[j] = Wl[k2 * 64 + fr * 4 + j];
        #pragma unroll
        for (int i = 0; i < 4; i++) {
            #pragma unroll
            for (int j = 0; j < 4; j++) {
#if __has_builtin(__builtin_amdgcn_fdot2)
                acc[i][j] = __builtin_amdgcn_fdot2(xa[i], wa[j], acc[i][j], false);
#else
                acc[i][j] += (float)xa[i].x * (float)wa[j].x + (float)xa[i].y * (float)wa[j].y;
#endif
            }
        }
    }
    #pragma unroll
    for (int i = 0; i < 4; i++) {
        int g = nbase + ng * 4 + i;
        if (g < N) {
            float dv = dinv[g];
            __half2 ha = __floats2half2_rn(acc[i][0] * dv, acc[i][1] * dv);
            __half2 hb = __floats2half2_rn(acc[i][2] * dv, acc[i][3] * dv);
            union { __half2 h[2]; uint2 u; } cvt;
            cvt.h[0] = ha; cvt.h[1] = hb;
            *(uint2*)(y16 + (size_t)g * FDIM + fr * 4) = cvt.u;
        }
    }
}

__device__ __forceinline__ float4 half4_to_float4(uint2 u) {
    float2 a = __half22float2(*(__half2*)&u.x);
    float2 b = __half22float2(*(__half2*)&u.y);
    return make_float4(a.x, a.y, b.x, b.y);
}

// ---- gather: out[n,:] = dinv[n]*(y[n,:] + sum_bucket y[src,:]) + b (+ReLU) ----
// 4 edge streams x 16-lane rows; 16-edge groups = 4 independent loads in flight.
template <bool RELU, typename OUT_T>
__global__ __launch_bounds__(256) void gather(const int* __restrict__ rowstart,
                                              const int* __restrict__ degv,
                                              const int* __restrict__ csr,
                                              const __half* __restrict__ y16,
                                              const float* __restrict__ dinv,
                                              const float* __restrict__ b,
                                              OUT_T* __restrict__ out, int N) {
    int lane = threadIdx.x & 63;
    int n = blockIdx.x * 4 + (threadIdx.x >> 6);
    if (n >= N) return;
    int q = lane >> 4;       // edge stream 0..3
    int fl = lane & 15;      // feature quad: feats 4fl..4fl+3
    int start = rowstart[n];
    int end = start + degv[n];
    // hoist self-loop row load: independent of edge loop, overlaps with it
    uint2 su = make_uint2(0u, 0u);
    if (q == 0) su = *(const uint2*)(y16 + (size_t)n * FDIM + 4 * fl);
    float ax = 0.f, ay = 0.f, az = 0.f, aw = 0.f;
    for (int base = start; base < end; base += 64) {
        int m = end - base; if (m > 64) m = 64;
        int idx = (lane < m) ? csr[base + lane] : 0;
        for (int j = 0; j < m; j += 16) {
            int e0 = j + q, e1 = j + 4 + q, e2 = j + 8 + q, e3 = j + 12 + q;
            int s0 = __shfl(idx, (e0 < m) ? e0 : (m - 1));
            int s1 = __shfl(idx, (e1 < m) ? e1 : (m - 1));
            int s2 = __shfl(idx, (e2 < m) ? e2 : (m - 1));
            int s3 = __shfl(idx, (e3 < m) ? e3 : (m - 1));
            uint2 u0 = *(const uint2*)(y16 + (size_t)s0 * FDIM + 4 * fl);
            uint2 u1 = *(const uint2*)(y16 + (size_t)s1 * FDIM + 4 * fl);
            uint2 u2 = *(const uint2*)(y16 + (size_t)s2 * FDIM + 4 * fl);
            uint2 u3 = *(const uint2*)(y16 + (size_t)s3 * FDIM + 4 * fl);
            if (e0 < m) { float4 f = half4_to_float4(u0); ax += f.x; ay += f.y; az += f.z; aw += f.w; }
            if (e1 < m) { float4 f = half4_to_float4(u1); ax += f.x; ay += f.y; az += f.z; aw += f.w; }
            if (e2 < m) { float4 f = half4_to_float4(u2); ax += f.x; ay += f.y; az += f.z; aw += f.w; }
            if (e3 < m) { float4 f = half4_to_float4(u3); ax += f.x; ay += f.y; az += f.z; aw += f.w; }
        }
    }
    // combine the 4 edge streams (lanes fl, fl+16, fl+32, fl+48)
    ax += __shfl_xor(ax, 16); ay += __shfl_xor(ay, 16);
    az += __shfl_xor(az, 16); aw += __shfl_xor(aw, 16);
    ax += __shfl_xor(ax, 32); ay += __shfl_xor(ay, 32);
    az += __shfl_xor(az, 32); aw += __shfl_xor(aw, 32);
    if (q == 0) {
        float4 sf = half4_to_float4(su);
        float dv = dinv[n];
        float4 bb = ((const float4*)b)[fl];
        float ox = (ax + sf.x) * dv + bb.x;
        float oy = (ay + sf.y) * dv + bb.y;
        float oz = (az + sf.z) * dv + bb.z;
        float ow = (aw + sf.w) * dv + bb.w;
        if (RELU) {
            ox = fmaxf(ox, 0.f); oy = fmaxf(oy, 0.f);
            oz = fmaxf(oz, 0.f); ow = fmaxf(ow, 0.f);
        }
        if constexpr (sizeof(OUT_T) == 2) {
            union { __half2 h[2]; uint2 u; } cvt;
            cvt.h[0] = __floats2half2_rn(ox, oy);
            cvt.h[1] = __floats2half2_rn(oz, ow);
            *(uint2*)((__half*)out + (size_t)n * FDIM + 4 * fl) = cvt.u;
        } else {
            *(float4*)((float*)out + (size_t)n * FDIM + 4 * fl) = make_float4(ox, oy, oz, ow);
        }
    }
}

static inline size_t roundup256(size_t x) { return (x + 255) & ~(size_t)255; }

extern "C" void kernel_launch(void* const* d_in, const int* in_sizes, int n_in,
                              void* d_out, int out_size, void* d_ws, size_t ws_size,
                              hipStream_t stream) {
    const float* x  = (const float*)d_in[0];
    const void*  ei = d_in[1];
    const float* W1 = (const float*)d_in[2];
    const float* b1 = (const float*)d_in[3];
    const float* W2 = (const float*)d_in[4];
    const float* b2 = (const float*)d_in[5];
    float* out = (float*)d_out;

    int N = out_size / FDIM;                       // 100000
    int E = in_sizes[1] / 2;                       // 1200000
    int nseg = (N + SEG - 1) >> SEG_SHIFT;         // 196
    if (nseg > NSEGMAX) nseg = NSEGMAX;            // (N<=131072 assumed)
    int nblk_p = (E + PB_EDGES - 1) / PB_EDGES;    // 293

    // ws layout (256B-aligned slots)
    char* p = (char*)d_ws;
    float* dinv    = (float*)p;  p += roundup256((size_t)N * 4);
    __half* y16    = (__half*)p; p += roundup256((size_t)N * FDIM * 2);
    __half* h16    = (__half*)p; p += roundup256((size_t)N * FDIM * 2);
    int* gcount    = (int*)p;    p += (size_t)NSEGMAX * GSTRIDE * 4;   // 8 KB
    int* flag      = (int*)p;    p += 256;
    int* rowstart  = (int*)p;    p += roundup256((size_t)N * 4);
    int* degv      = (int*)p;    p += roundup256((size_t)N * 4);
    int* csr       = (int*)p;    p += (size_t)nseg * SCAP * 4;         // ~6.4 MB
    int2* parts    = (int2*)p;   p += (size_t)nseg * SCAP * sizeof(int2);  // ~12.8 MB

    // ---- graph prep: detect dtype + zero gcount, slab by segment, counting sort ----
    detect_dtype_kernel<<<1, 256, 0, stream>>>((const int*)ei, 2048, flag,
                                               gcount, NSEGMAX * GSTRIDE);
    bucket_place<<<nblk_p, 256, 0, stream>>>(ei, flag, E, nseg, gcount, parts);
    place_sort<<<nseg, 256, 0, stream>>>(parts, gcount, csr, rowstart, degv, dinv, N);

    int gemm_grid = (N + 63) / 64;
    int gath_grid = (N + 3) / 4;

    // ---- layer 1: h = relu(GCNConv(x, W1, b1)) -> h16 (fp16) ----
    gemm_scale<float><<<gemm_grid, 256, 0, stream>>>(x, W1, dinv, y16, N);
    gather<true, __half><<<gath_grid, 256, 0, stream>>>(rowstart, degv, csr, y16, dinv, b1, h16, N);

    // ---- layer 2: out = GCNConv(h, W2, b2) -> fp32 d_out ----
    gemm_scale<__half><<<gemm_grid, 256, 0, stream>>>(h16, W2, dinv, y16, N);
    gather<false, float><<<gath_grid, 256, 0, stream>>>(rowstart, degv, csr, y16, dinv, b2, out, N);
}

// Round 15
// 152.386 us; speedup vs baseline: 7.3862x; 1.0244x over previous
//
#include <hip/hip_runtime.h>
#include <hip/hip_fp16.h>

#define FDIM 64
#define SEG 512               // nodes per segment
#define SEG_SHIFT 9
#define NSEGMAX 256
#define SCAP 8192             // slots per segment slab (mean ~6.1K, ~26 sigma headroom)
#define GSTRIDE 8             // ints between per-segment counters
#define PB_EDGES 4096         // edges per bucket_place block (293 blocks > 256 CUs)

typedef _Float16 h2_t __attribute__((ext_vector_type(2)));

// ---- detect int64 vs int32 edge_index + zero gcount ----
__global__ void detect_dtype_kernel(const int* ei, int nsamp, int* flag, int* gcount, int glen) {
    __shared__ int any_nz;
    if (threadIdx.x == 0) any_nz = 0;
    __syncthreads();
    int local = 0;
    for (int i = threadIdx.x; i < nsamp; i += blockDim.x) {
        if (ei[2 * i + 1] != 0) local = 1;   // odd dword: int64 high word (==0) vs real int32 index
    }
    if (local) atomicOr(&any_nz, 1);
    for (int i = threadIdx.x; i < glen; i += blockDim.x) gcount[i] = 0;
    __syncthreads();
    if (threadIdx.x == 0) flag[0] = (any_nz == 0) ? 1 : 0;   // 1 => int64
}

// ---- pass 1 over edges: slab (s,d) by segment d>>9. LDS histogram; one global
// atomic per (block,segment); NO per-edge global atomics. ----
__global__ __launch_bounds__(256) void bucket_place(const void* ei, const int* flag, int E,
                                                    int nseg,
                                                    int* __restrict__ gcount,
                                                    int2* __restrict__ parts) {
    __shared__ int lhist[NSEGMAX];
    __shared__ int lbase[NSEGMAX];
    __shared__ int loff[NSEGMAX];
    int is64 = flag[0];
    int t = threadIdx.x;
    const long long* q64 = (const long long*)ei;
    const int* q32 = (const int*)ei;
    int base = blockIdx.x * PB_EDGES;
    for (int i = t; i < nseg; i += 256) { lhist[i] = 0; loff[i] = 0; }
    __syncthreads();
    // phase A: local histogram (dst only)
    #pragma unroll 4
    for (int u = 0; u < PB_EDGES / 256; u++) {
        int i = base + u * 256 + t;
        if (i < E) {
            int d = is64 ? (int)q64[E + i] : q32[E + i];
            atomicAdd(&lhist[d >> SEG_SHIFT], 1);
        }
    }
    __syncthreads();
    // reserve: one global atomic per touched segment
    for (int i = t; i < nseg; i += 256)
        lbase[i] = (lhist[i] > 0) ? atomicAdd(&gcount[i * GSTRIDE], lhist[i]) : 0;
    __syncthreads();
    // phase B: re-read (cache-hot), rank via LDS rtn-atomic, write runs
    #pragma unroll 4
    for (int u = 0; u < PB_EDGES / 256; u++) {
        int i = base + u * 256 + t;
        if (i < E) {
            int s, d;
            if (is64) { s = (int)q64[i]; d = (int)q64[E + i]; }
            else      { s = q32[i];      d = q32[E + i]; }
            int bk = d >> SEG_SHIFT;
            int off = atomicAdd(&loff[bk], 1);
            int pos = lbase[bk] + off;
            if (pos < SCAP) parts[(size_t)bk * SCAP + pos] = make_int2(s, d);
        }
    }
}

// ---- pass 2: per-segment counting sort. One block per 512-node segment:
// LDS hist -> LDS scan -> rowstart/deg/dinv (coalesced) -> place src into csr
// via LDS cursor atomics. csr scatter stays inside a 32KB L2-resident window. ----
__global__ __launch_bounds__(256) void place_sort(const int2* __restrict__ parts,
                                                  const int* __restrict__ gcount,
                                                  int* __restrict__ csr,
                                                  int* __restrict__ rowstart,
                                                  int* __restrict__ degv,
                                                  float* __restrict__ dinv, int N) {
    __shared__ int hist[SEG];
    __shared__ int cur[SEG];
    __shared__ int A[256], B[256];
    int s = blockIdx.x;
    int t = threadIdx.x;
    int nbase = s << SEG_SHIFT;
    hist[t] = 0; hist[t + 256] = 0;
    __syncthreads();
    int cnt = gcount[s * GSTRIDE]; if (cnt > SCAP) cnt = SCAP;
    const int2* pg = parts + (size_t)s * SCAP;
    for (int j = t; j < cnt; j += 256) atomicAdd(&hist[pg[j].y & (SEG - 1)], 1);
    __syncthreads();
    // exclusive scan over 512 via pair-sum + 256-wide Hillis-Steele
    int p = hist[2 * t] + hist[2 * t + 1];
    A[t] = p; __syncthreads();
    int* in = A; int* out = B;
    for (int off = 1; off < 256; off <<= 1) {
        out[t] = in[t] + ((t >= off) ? in[t - off] : 0);
        __syncthreads();
        int* z = in; in = out; out = z;
    }
    int esc = (t == 0) ? 0 : in[t - 1];
    cur[2 * t] = esc;
    cur[2 * t + 1] = esc + hist[2 * t];
    __syncthreads();
    // emit per-node metadata (coalesced)
    for (int i = t; i < SEG; i += 256) {
        int n = nbase + i;
        if (n < N) {
            rowstart[n] = s * SCAP + cur[i];
            degv[n] = hist[i];
            dinv[n] = rsqrtf((float)(hist[i] + 1));
        }
    }
    __syncthreads();
    // place: LDS cursor atomics only
    for (int j = t; j < cnt; j += 256) {
        int2 e = pg[j];
        int r = e.y & (SEG - 1);
        int off = atomicAdd(&cur[r], 1);
        csr[(size_t)s * SCAP + off] = e.x;
    }
}

// ---- y16[n,:] = half((x[n,:] @ W) * dinv[n]) — LDS-tiled 64x64, fp16 dot2 ----
template <typename TIN>
__global__ __launch_bounds__(256, 4) void gemm_scale(const TIN* __restrict__ x,
                                                     const float* __restrict__ W,
                                                     const float* __restrict__ dinv,
                                                     __half* __restrict__ y16, int N) {
    __shared__ h2_t Xl[64 * 34];    // [node][k2], pad 34 to break bank aliasing
    __shared__ h2_t Wl[32 * 64];    // [k2][feat] = (W[2k2][f], W[2k2+1][f])
    int t = threadIdx.x;
    int nbase = blockIdx.x * 64;
    // stage W packed over k-pairs (coalesced over f)
    for (int i = t; i < 2048; i += 256) {
        int k2 = i >> 6, f = i & 63;
        float w0 = W[(2 * k2) * FDIM + f];
        float w1 = W[(2 * k2 + 1) * FDIM + f];
        h2_t pk; pk.x = (_Float16)w0; pk.y = (_Float16)w1;
        Wl[i] = pk;
    }
    // stage X tile as half2 pairs
    for (int i = t; i < 1024; i += 256) {
        int flat = i * 4;
        int n = flat >> 6, k = flat & 63;
        int g = nbase + n;
        h2_t a, c;
        if (g < N) {
            if constexpr (sizeof(TIN) == 2) {
                uint2 u = *(const uint2*)((const __half*)x + (size_t)g * FDIM + k);
                a = *(h2_t*)&u.x; c = *(h2_t*)&u.y;
            } else {
                float4 v = *(const float4*)((const float*)x + (size_t)g * FDIM + k);
                a.x = (_Float16)v.x; a.y = (_Float16)v.y;
                c.x = (_Float16)v.z; c.y = (_Float16)v.w;
            }
        } else {
            a.x = (_Float16)0.f; a.y = (_Float16)0.f; c = a;
        }
        Xl[n * 34 + (k >> 1)] = a;
        Xl[n * 34 + (k >> 1) + 1] = c;
    }
    __syncthreads();

    int fr = t & 15;    // feature group: feats fr*4..fr*4+3
    int ng = t >> 4;    // node group:    nodes ng*4..ng*4+3
    float acc[4][4] = {{0.f}};
    #pragma unroll 8
    for (int k2 = 0; k2 < 32; k2++) {
        h2_t xa[4], wa[4];
        #pragma unroll
        for (int i = 0; i < 4; i++) xa[i] = Xl[(ng * 4 + i) * 34 + k2];
        #pragma unroll
        for (int j = 0; j < 4; j++) wa[j] = Wl[k2 * 64 + fr * 4 + j];
        #pragma unroll
        for (int i = 0; i < 4; i++) {
            #pragma unroll
            for (int j = 0; j < 4; j++) {
#if __has_builtin(__builtin_amdgcn_fdot2)
                acc[i][j] = __builtin_amdgcn_fdot2(xa[i], wa[j], acc[i][j], false);
#else
                acc[i][j] += (float)xa[i].x * (float)wa[j].x + (float)xa[i].y * (float)wa[j].y;
#endif
            }
        }
    }
    #pragma unroll
    for (int i = 0; i < 4; i++) {
        int g = nbase + ng * 4 + i;
        if (g < N) {
            float dv = dinv[g];
            __half2 ha = __floats2half2_rn(acc[i][0] * dv, acc[i][1] * dv);
            __half2 hb = __floats2half2_rn(acc[i][2] * dv, acc[i][3] * dv);
            union { __half2 h[2]; uint2 u; } cvt;
            cvt.h[0] = ha; cvt.h[1] = hb;
            *(uint2*)(y16 + (size_t)g * FDIM + fr * 4) = cvt.u;
        }
    }
}

__device__ __forceinline__ float4 half4_to_float4(uint2 u) {
    float2 a = __half22float2(*(__half2*)&u.x);
    float2 b = __half22float2(*(__half2*)&u.y);
    return make_float4(a.x, a.y, b.x, b.y);
}

// ---- gather: out[n,:] = dinv[n]*(y[n,:] + sum_bucket y[src,:]) + b (+ReLU) ----
// 4 edge streams x 16-lane rows; 16-edge groups, 4 loads in flight.
// Hot loop is UNCONDITIONAL: invalid slots clamp to row m-1; the overcount
// (c copies of row m-1, u3's quad) is removed by one fused-multiply correction.
template <bool RELU, typename OUT_T>
__global__ __launch_bounds__(256) void gather(const int* __restrict__ rowstart,
                                              const int* __restrict__ degv,
                                              const int* __restrict__ csr,
                                              const __half* __restrict__ y16,
                                              const float* __restrict__ dinv,
                                              const float* __restrict__ b,
                                              OUT_T* __restrict__ out, int N) {
    int lane = threadIdx.x & 63;
    int n = blockIdx.x * 4 + (threadIdx.x >> 6);
    if (n >= N) return;
    int q = lane >> 4;       // edge stream 0..3
    int fl = lane & 15;      // feature quad: feats 4fl..4fl+3
    int start = rowstart[n];
    int end = start + degv[n];
    // hoist self-loop row load: independent of edge loop, overlaps with it
    uint2 su = make_uint2(0u, 0u);
    if (q == 0) su = *(const uint2*)(y16 + (size_t)n * FDIM + 4 * fl);
    float ax = 0.f, ay = 0.f, az = 0.f, aw = 0.f;
    for (int base = start; base < end; base += 64) {
        int m = end - base; if (m > 64) m = 64;
        int idx = (lane < m) ? csr[base + lane] : 0;
        for (int j = 0; j < m; j += 16) {
            int e0 = j + q, e1 = j + 4 + q, e2 = j + 8 + q, e3 = j + 12 + q;
            int s0 = __shfl(idx, (e0 < m) ? e0 : (m - 1));
            int s1 = __shfl(idx, (e1 < m) ? e1 : (m - 1));
            int s2 = __shfl(idx, (e2 < m) ? e2 : (m - 1));
            int s3 = __shfl(idx, (e3 < m) ? e3 : (m - 1));
            uint2 u0 = *(const uint2*)(y16 + (size_t)s0 * FDIM + 4 * fl);
            uint2 u1 = *(const uint2*)(y16 + (size_t)s1 * FDIM + 4 * fl);
            uint2 u2 = *(const uint2*)(y16 + (size_t)s2 * FDIM + 4 * fl);
            uint2 u3 = *(const uint2*)(y16 + (size_t)s3 * FDIM + 4 * fl);
            float4 f0 = half4_to_float4(u0);
            float4 f1 = half4_to_float4(u1);
            float4 f2 = half4_to_float4(u2);
            float4 f3 = half4_to_float4(u3);
            // unconditional tree accumulate of all 4 rows
            ax += (f0.x + f1.x) + (f2.x + f3.x);
            ay += (f0.y + f1.y) + (f2.y + f3.y);
            az += (f0.z + f1.z) + (f2.z + f3.z);
            aw += (f0.w + f1.w) + (f2.w + f3.w);
            // subtract the c clamped duplicates of row m-1 (all held in u3's quad:
            // if any e_i >= m then e3 >= m, so u3 == row[m-1])
            int v = m - j - q;                               // #valid among e0..e3 * 4
            int nv = (v >= 16) ? 4 : ((v <= 0) ? 0 : ((v + 3) >> 2));
            float c = (float)(4 - nv);
            ax = fmaf(-c, f3.x, ax);
            ay = fmaf(-c, f3.y, ay);
            az = fmaf(-c, f3.z, az);
            aw = fmaf(-c, f3.w, aw);
        }
    }
    // combine the 4 edge streams (lanes fl, fl+16, fl+32, fl+48)
    ax += __shfl_xor(ax, 16); ay += __shfl_xor(ay, 16);
    az += __shfl_xor(az, 16); aw += __shfl_xor(aw, 16);
    ax += __shfl_xor(ax, 32); ay += __shfl_xor(ay, 32);
    az += __shfl_xor(az, 32); aw += __shfl_xor(aw, 32);
    if (q == 0) {
        float4 sf = half4_to_float4(su);
        float dv = dinv[n];
        float4 bb = ((const float4*)b)[fl];
        float ox = (ax + sf.x) * dv + bb.x;
        float oy = (ay + sf.y) * dv + bb.y;
        float oz = (az + sf.z) * dv + bb.z;
        float ow = (aw + sf.w) * dv + bb.w;
        if (RELU) {
            ox = fmaxf(ox, 0.f); oy = fmaxf(oy, 0.f);
            oz = fmaxf(oz, 0.f); ow = fmaxf(ow, 0.f);
        }
        if constexpr (sizeof(OUT_T) == 2) {
            union { __half2 h[2]; uint2 u; } cvt;
            cvt.h[0] = __floats2half2_rn(ox, oy);
            cvt.h[1] = __floats2half2_rn(oz, ow);
            *(uint2*)((__half*)out + (size_t)n * FDIM + 4 * fl) = cvt.u;
        } else {
            *(float4*)((float*)out + (size_t)n * FDIM + 4 * fl) = make_float4(ox, oy, oz, ow);
        }
    }
}

static inline size_t roundup256(size_t x) { return (x + 255) & ~(size_t)255; }

extern "C" void kernel_launch(void* const* d_in, const int* in_sizes, int n_in,
                              void* d_out, int out_size, void* d_ws, size_t ws_size,
                              hipStream_t stream) {
    const float* x  = (const float*)d_in[0];
    const void*  ei = d_in[1];
    const float* W1 = (const float*)d_in[2];
    const float* b1 = (const float*)d_in[3];
    const float* W2 = (const float*)d_in[4];
    const float* b2 = (const float*)d_in[5];
    float* out = (float*)d_out;

    int N = out_size / FDIM;                       // 100000
    int E = in_sizes[1] / 2;                       // 1200000
    int nseg = (N + SEG - 1) >> SEG_SHIFT;         // 196
    if (nseg > NSEGMAX) nseg = NSEGMAX;            // (N<=131072 assumed)
    int nblk_p = (E + PB_EDGES - 1) / PB_EDGES;    // 293

    // ws layout (256B-aligned slots)
    char* p = (char*)d_ws;
    float* dinv    = (float*)p;  p += roundup256((size_t)N * 4);
    __half* y16    = (__half*)p; p += roundup256((size_t)N * FDIM * 2);
    __half* h16    = (__half*)p; p += roundup256((size_t)N * FDIM * 2);
    int* gcount    = (int*)p;    p += (size_t)NSEGMAX * GSTRIDE * 4;   // 8 KB
    int* flag      = (int*)p;    p += 256;
    int* rowstart  = (int*)p;    p += roundup256((size_t)N * 4);
    int* degv      = (int*)p;    p += roundup256((size_t)N * 4);
    int* csr       = (int*)p;    p += (size_t)nseg * SCAP * 4;         // ~6.4 MB
    int2* parts    = (int2*)p;   p += (size_t)nseg * SCAP * sizeof(int2);  // ~12.8 MB

    // ---- graph prep: detect dtype + zero gcount, slab by segment, counting sort ----
    detect_dtype_kernel<<<1, 256, 0, stream>>>((const int*)ei, 2048, flag,
                                               gcount, NSEGMAX * GSTRIDE);
    bucket_place<<<nblk_p, 256, 0, stream>>>(ei, flag, E, nseg, gcount, parts);
    place_sort<<<nseg, 256, 0, stream>>>(parts, gcount, csr, rowstart, degv, dinv, N);

    int gemm_grid = (N + 63) / 64;
    int gath_grid = (N + 3) / 4;

    // ---- layer 1: h = relu(GCNConv(x, W1, b1)) -> h16 (fp16) ----
    gemm_scale<float><<<gemm_grid, 256, 0, stream>>>(x, W1, dinv, y16, N);
    gather<true, __half><<<gath_grid, 256, 0, stream>>>(rowstart, degv, csr, y16, dinv, b1, h16, N);

    // ---- layer 2: out = GCNConv(h, W2, b2) -> fp32 d_out ----
    gemm_scale<__half><<<gemm_grid, 256, 0, stream>>>(h16, W2, dinv, y16, N);
    gather<false, float><<<gath_grid, 256, 0, stream>>>(rowstart, degv, csr, y16, dinv, b2, out, N);
}